// Round 7
// baseline (68.542 us; speedup 1.0000x reference)
//
#include <hip/hip_runtime.h>
#include <hip/hip_bf16.h>

using u16 = unsigned short;
using u32 = unsigned int;

typedef float f32x4 __attribute__((ext_vector_type(4)));
typedef __bf16 bf16x8 __attribute__((ext_vector_type(8)));

constexpr int B_ = 2;
constexpr int S_ = 4096;
constexpr int D_ = 512;
constexpr int H_ = 8;
constexpr int DK_ = 64;
constexpr int M_ = B_ * S_;   // 8192
constexpr int K_ = 512;

__device__ __forceinline__ float bf2f(u16 u) {
  return __uint_as_float(((u32)u) << 16);
}
// fp32 -> bf16 round-to-nearest-even (inputs finite)
__device__ __forceinline__ u16 f2bf(float x) {
  u32 u = __float_as_uint(x);
  u = (u + 0x7fffu + ((u >> 16) & 1u)) >> 16;
  return (u16)u;
}
__device__ __forceinline__ u32 pack2(float a, float b) {
  return (u32)f2bf(a) | ((u32)f2bf(b) << 16);
}

// async global->LDS, 16B per lane; LDS dest = wave-uniform base + lane*16
__device__ __forceinline__ void gload16(const u16* g, u16* l) {
  __builtin_amdgcn_global_load_lds((const __attribute__((address_space(1))) void*)g,
                                   (__attribute__((address_space(3))) void*)l,
                                   16, 0, 0);
}

// ---------------------------------------------------------------------------
// Prepass: convert the FOUR weight matrices to bf16 (1M elems, ~1.5us).
// Activations are converted inside gemm_qkv now.
// ---------------------------------------------------------------------------
constexpr int NG_W = 4 * (262144 / 8);   // 131072 groups

__global__ __launch_bounds__(256) void convert_w(
    const float* __restrict__ wq, const float* __restrict__ wk,
    const float* __restrict__ wv, const float* __restrict__ wo,
    u16* __restrict__ wqb, u16* __restrict__ wkb, u16* __restrict__ wvb,
    u16* __restrict__ wob)
{
  const int g8 = blockIdx.x * 256 + threadIdx.x;
  if (g8 >= NG_W) return;
  const int t = g8 >> 15;          // 32768 groups per matrix
  const int r = g8 & 32767;
  const float* s = (t == 0) ? wq : (t == 1) ? wk : (t == 2) ? wv : wo;
  u16* d = (t == 0) ? wqb : (t == 1) ? wkb : (t == 2) ? wvb : wob;
  const size_t off = (size_t)r * 8;
  const float4 x = *(const float4*)(s + off);
  const float4 y = *(const float4*)(s + off + 4);
  uint4 o;
  o.x = pack2(x.x, x.y); o.y = pack2(x.z, x.w);
  o.z = pack2(y.x, y.y); o.w = pack2(y.z, y.w);
  *(uint4*)(d + off) = o;
}

// ---------------------------------------------------------------------------
// QKV GEMM with fp32 A (in-kernel convert):
//   C[m][n] = sum_k A[m][k] * W[n][k] + bias[n],  A fp32 [M,512], W bf16.
// MODE 1: bf16 head-split [bh][s][d]; MODE 2: transposed [bh][d][s].
// Tile 128x128, BK=64, 4 waves (2x2), wave tile 64x64, single 32KB LDS buf.
// A: global fp32 -> reg -> cvt_pk -> ds_write_b128 at XOR-swizzled addr
//    (T14 split: passes 0-1 loads issued before compute, written after bar).
// B: global_load_lds 16B, linear dest + pre-swizzled source (T21).
// Read side XOR (qr&7)<<4 matches both write paths.
// ---------------------------------------------------------------------------
template<int MODE>
__device__ __forceinline__ void gemm_body_f32A(const float* __restrict__ A,
                                               const u16* __restrict__ Wt,
                                               const float* __restrict__ bias,
                                               void* __restrict__ Cout,
                                               u16* __restrict__ As,
                                               u16* __restrict__ Bs)
{
  const int tid  = threadIdx.x;
  const int lane = tid & 63;
  const int w    = tid >> 6;
  const int wm   = w >> 1;          // wave row: 64 m each
  const int wn   = w & 1;           // wave col: 64 n each
  const int m0   = blockIdx.x * 128;
  const int n0   = blockIdx.y * 128;
  const int qr   = lane & 15;
  const int g    = lane >> 4;

  // ---- A staging (fp32 -> bf16, reg path, swizzled ds_write) ----
  const int sr8 = tid >> 3;         // row 0..31 (+p*32)
  const int c8  = tid & 7;          // 8-elem col chunk
  const float* afp = A + (size_t)(m0 + sr8) * K_ + c8 * 8;
  char* awr = (char*)As + sr8 * 128 + ((c8 ^ (sr8 & 7)) * 16);  // swizzled

  auto a_load = [&](int t, int p, float4& x, float4& y) {
    const float* s = afp + t * 64 + (size_t)p * 32 * K_;
    x = *(const float4*)s;
    y = *(const float4*)(s + 4);
  };
  auto a_write = [&](int p, const float4& x, const float4& y) {
    uint4 o;
    o.x = pack2(x.x, x.y); o.y = pack2(x.z, x.w);
    o.z = pack2(y.x, y.y); o.w = pack2(y.z, y.w);
    *(uint4*)(awr + p * 32 * 128) = o;
  };

  // ---- B staging (bf16 via global_load_lds, source pre-swizzle) ----
  const int swz8 = ((lane & 7) ^ (lane >> 3)) * 8;   // elems
  const u16* b0 = Wt + (size_t)(n0 + w * 32 + (lane >> 3)) * K_ + swz8;
  auto stage_B = [&](int t) {
#pragma unroll
    for (int p = 0; p < 4; ++p)
      gload16(b0 + t * 64 + (size_t)p * 8 * K_, &Bs[(w * 32 + p * 8) * 64]);
  };

  f32x4 acc[4][4] = {};

  // prologue: full stage of tile 0
  {
    float4 x0, y0, x1, y1, x2, y2, x3, y3;
    a_load(0, 0, x0, y0); a_load(0, 1, x1, y1);
    a_load(0, 2, x2, y2); a_load(0, 3, x3, y3);
    a_write(0, x0, y0); a_write(1, x1, y1);
    a_write(2, x2, y2); a_write(3, x3, y3);
    stage_B(0);
  }

  const int ax = (qr & 7) << 4;   // row-XOR for swizzled ds_read
  const char* ab = (const char*)As + (wm * 64 + qr) * 128;
  const char* bb = (const char*)Bs + (wn * 64 + qr) * 128;

  constexpr int NT = K_ / 64;  // 8
#pragma unroll 1
  for (int t = 0; t < NT; ++t) {
    __syncthreads();   // stage(t) drained (vmcnt+lgkm) + visible

    float4 xa, ya, xb, yb;
    if (t + 1 < NT) {  // T14: issue first half of next A-tile loads now
      a_load(t + 1, 0, xa, ya);
      a_load(t + 1, 1, xb, yb);
    }

#pragma unroll
    for (int kk = 0; kk < 2; ++kk) {
      bf16x8 af[4], bfr[4];
#pragma unroll
      for (int i = 0; i < 4; ++i)
        af[i]  = *(const bf16x8*)(ab + i * 2048 + ((g * 16 + kk * 64) ^ ax));
#pragma unroll
      for (int j = 0; j < 4; ++j)
        bfr[j] = *(const bf16x8*)(bb + j * 2048 + ((g * 16 + kk * 64) ^ ax));
#pragma unroll
      for (int i = 0; i < 4; ++i)
#pragma unroll
        for (int j = 0; j < 4; ++j)
          acc[i][j] = __builtin_amdgcn_mfma_f32_16x16x32_bf16(af[i], bfr[j], acc[i][j], 0, 0, 0);
    }

    if (t + 1 < NT) {
      __syncthreads();           // all waves done reading buffer
      a_write(0, xa, ya); a_write(1, xb, yb);
      float4 xc, yc, xd, yd;
      a_load(t + 1, 2, xc, yc); a_load(t + 1, 3, xd, yd);
      a_write(2, xc, yc); a_write(3, xd, yd);
      stage_B(t + 1);
    }
  }

  // epilogue: D frag layout col(n) = lane&15, row(m) = 4*(lane>>4)+r
#pragma unroll
  for (int j = 0; j < 4; ++j) {
    const int col = n0 + wn * 64 + j * 16 + qr;
    const float bv = bias[col];
#pragma unroll
    for (int i = 0; i < 4; ++i) {
      const int rbase = m0 + wm * 64 + i * 16 + g * 4;
      if constexpr (MODE == 2) {
        const int bb2 = rbase >> 12;
        const int ss = rbase & (S_ - 1);
        const int hh = col >> 6;
        const int dd = col & (DK_ - 1);
        uint2 pk;
        pk.x = pack2(acc[i][j][0] + bv, acc[i][j][1] + bv);
        pk.y = pack2(acc[i][j][2] + bv, acc[i][j][3] + bv);
        *(uint2*)&((u16*)Cout)[((size_t)((bb2 * H_ + hh) * DK_ + dd)) * S_ + ss] = pk;
      } else {
#pragma unroll
        for (int r = 0; r < 4; ++r) {
          const int row = rbase + r;
          const int bb2 = row >> 12;
          const int ss = row & (S_ - 1);
          const int hh = col >> 6;
          const int dd = col & (DK_ - 1);
          ((u16*)Cout)[((size_t)(bb2 * H_ + hh) * S_ + ss) * DK_ + dd] =
              f2bf(acc[i][j][r] + bv);
        }
      }
    }
  }
}

__global__ __launch_bounds__(256, 4) void gemm_qkv(
    const float* __restrict__ q, const float* __restrict__ k, const float* __restrict__ v,
    const u16* __restrict__ wqb, const u16* __restrict__ wkb, const u16* __restrict__ wvb,
    const float* __restrict__ bq, const float* __restrict__ bk, const float* __restrict__ bv,
    u16* __restrict__ Qo, u16* __restrict__ Ko, u16* __restrict__ Vo)
{
  __shared__ u16 As[128 * 64];
  __shared__ u16 Bs[128 * 64];
  if (blockIdx.z == 0)      gemm_body_f32A<1>(q, wqb, bq, Qo, As, Bs);
  else if (blockIdx.z == 1) gemm_body_f32A<1>(k, wkb, bk, Ko, As, Bs);
  else                      gemm_body_f32A<2>(v, wvb, bv, Vo, As, Bs);  // V transposed
}

// ---------------------------------------------------------------------------
// Output GEMM: A bf16 (ctx), W bf16, fp32 out [M,512]. Both operands via
// global_load_lds (linear dest + pre-swizzled source), single LDS buffer.
// ---------------------------------------------------------------------------
__global__ __launch_bounds__(256, 4) void gemm_out(
    const u16* __restrict__ A, const u16* __restrict__ Wt,
    const float* __restrict__ bias, float* __restrict__ C)
{
  __shared__ u16 As[128 * 64];
  __shared__ u16 Bs[128 * 64];

  const int tid  = threadIdx.x;
  const int lane = tid & 63;
  const int w    = tid >> 6;
  const int wm   = w >> 1;
  const int wn   = w & 1;
  const int m0   = blockIdx.x * 128;
  const int n0   = blockIdx.y * 128;
  const int qr   = lane & 15;
  const int g    = lane >> 4;

  const int swz8 = ((lane & 7) ^ (lane >> 3)) * 8;
  const u16* a0 = A  + (size_t)(m0 + w * 32 + (lane >> 3)) * K_ + swz8;
  const u16* b0 = Wt + (size_t)(n0 + w * 32 + (lane >> 3)) * K_ + swz8;

  auto stage = [&](int t) {
#pragma unroll
    for (int p = 0; p < 4; ++p)
      gload16(a0 + t * 64 + (size_t)p * 8 * K_, &As[(w * 32 + p * 8) * 64]);
#pragma unroll
    for (int p = 0; p < 4; ++p)
      gload16(b0 + t * 64 + (size_t)p * 8 * K_, &Bs[(w * 32 + p * 8) * 64]);
  };

  f32x4 acc[4][4] = {};
  stage(0);

  const int ax = (qr & 7) << 4;
  const char* ab = (const char*)As + (wm * 64 + qr) * 128;
  const char* bb = (const char*)Bs + (wn * 64 + qr) * 128;

  constexpr int NT = K_ / 64;
#pragma unroll 1
  for (int t = 0; t < NT; ++t) {
    __syncthreads();
#pragma unroll
    for (int kk = 0; kk < 2; ++kk) {
      bf16x8 af[4], bfr[4];
#pragma unroll
      for (int i = 0; i < 4; ++i)
        af[i]  = *(const bf16x8*)(ab + i * 2048 + ((g * 16 + kk * 64) ^ ax));
#pragma unroll
      for (int j = 0; j < 4; ++j)
        bfr[j] = *(const bf16x8*)(bb + j * 2048 + ((g * 16 + kk * 64) ^ ax));
#pragma unroll
      for (int i = 0; i < 4; ++i)
#pragma unroll
        for (int j = 0; j < 4; ++j)
          acc[i][j] = __builtin_amdgcn_mfma_f32_16x16x32_bf16(af[i], bfr[j], acc[i][j], 0, 0, 0);
    }
    if (t + 1 < NT) {
      __syncthreads();
      stage(t + 1);
    }
  }

#pragma unroll
  for (int j = 0; j < 4; ++j) {
    const int col = n0 + wn * 64 + j * 16 + qr;
    const float bv = bias[col];
#pragma unroll
    for (int i = 0; i < 4; ++i) {
      const int rbase = m0 + wm * 64 + i * 16 + g * 4;
#pragma unroll
      for (int r = 0; r < 4; ++r)
        C[(size_t)(rbase + r) * D_ + col] = acc[i][j][r] + bv;
    }
  }
}

// ---------------------------------------------------------------------------
// MFMA banded attention (unchanged). One wave per 16-query tile.
// ---------------------------------------------------------------------------
__global__ __launch_bounds__(256) void attn_band_mfma(
    const u16* __restrict__ Q, const u16* __restrict__ K,
    const u16* __restrict__ Vt, u16* __restrict__ Ctx)
{
  constexpr int LDP = 72;
  __shared__ u16 P_lds[4][16 * LDP];

  const int lane = threadIdx.x & 63;
  const int w    = threadIdx.x >> 6;
  const int wid  = blockIdx.x * 4 + w;
  const int q0   = (wid & 255) << 4;
  const int bh   = wid >> 8;
  const size_t kbase = (size_t)bh * S_ * DK_;

  u16* pl = &P_lds[w][0];
  const int qr = lane & 15;
  const int g  = lane >> 4;

  *(uint2*)&pl[qr * LDP + 48 + 4 * g] = make_uint2(0u, 0u);

  bf16x8 qf[2];
  {
    const u16* qp = Q + kbase + (size_t)(q0 + qr) * DK_ + 8 * g;
    qf[0] = *(const bf16x8*)qp;
    qf[1] = *(const bf16x8*)(qp + 32);
  }

  f32x4 sc[3];
#pragma unroll
  for (int t = 0; t < 3; ++t) {
    int j = q0 - 16 + 16 * t + qr;
    j = min(max(j, 0), S_ - 1);
    const u16* kp = K + kbase + (size_t)j * DK_ + 8 * g;
    const bf16x8 kf0 = *(const bf16x8*)kp;
    const bf16x8 kf1 = *(const bf16x8*)(kp + 32);
    f32x4 a = {};
    a = __builtin_amdgcn_mfma_f32_16x16x32_bf16(kf0, qf[0], a, 0, 0, 0);
    a = __builtin_amdgcn_mfma_f32_16x16x32_bf16(kf1, qf[1], a, 0, 0, 0);
    sc[t] = a;
  }

  float s[3][4];
  float mx = -INFINITY;
#pragma unroll
  for (int t = 0; t < 3; ++t)
#pragma unroll
    for (int r = 0; r < 4; ++r) {
      const int joff = 16 * t + 4 * g + r;
      const int j = q0 - 16 + joff;
      const bool ok = (joff >= qr) && (joff <= qr + 32) && (j >= 0) && (j < S_);
      const float v = ok ? sc[t][r] * 0.125f : -INFINITY;
      s[t][r] = v;
      mx = fmaxf(mx, v);
    }
  mx = fmaxf(mx, __shfl_xor(mx, 16));
  mx = fmaxf(mx, __shfl_xor(mx, 32));

  float p[3][4];
  float den = 0.f;
#pragma unroll
  for (int t = 0; t < 3; ++t)
#pragma unroll
    for (int r = 0; r < 4; ++r) {
      p[t][r] = __expf(s[t][r] - mx);
      den += p[t][r];
    }
  den += __shfl_xor(den, 16);
  den += __shfl_xor(den, 32);
  const float inv = 1.0f / den;

#pragma unroll
  for (int t = 0; t < 3; ++t) {
    uint2 pk;
    pk.x = pack2(p[t][0] * inv, p[t][1] * inv);
    pk.y = pack2(p[t][2] * inv, p[t][3] * inv);
    *(uint2*)&pl[qr * LDP + 16 * t + 4 * g] = pk;
  }

  f32x4 cacc[4] = {};
#pragma unroll
  for (int jc = 0; jc < 2; ++jc) {
    const bf16x8 pa = *(const bf16x8*)&pl[qr * LDP + 8 * g + 32 * jc];
#pragma unroll
    for (int nt = 0; nt < 4; ++nt) {
      int jj = q0 - 16 + 8 * g + 32 * jc;
      jj = min(max(jj, 0), S_ - 8);
      const u16* vp = Vt + ((size_t)bh * DK_ + 16 * nt + qr) * S_ + jj;
      const bf16x8 vf = *(const bf16x8*)vp;
      cacc[nt] = __builtin_amdgcn_mfma_f32_16x16x32_bf16(pa, vf, cacc[nt], 0, 0, 0);
    }
  }

  const int bb = bh >> 3;
  const int hh = bh & (H_ - 1);
#pragma unroll
  for (int nt = 0; nt < 4; ++nt)
#pragma unroll
    for (int r = 0; r < 4; ++r) {
      const int qq = 4 * g + r;
      const int dd = 16 * nt + qr;
      Ctx[((size_t)(bb * S_ + q0 + qq)) * D_ + hh * DK_ + dd] = f2bf(cacc[nt][r]);
    }
}

// ---------------------------------------------------------------------------
extern "C" void kernel_launch(void* const* d_in, const int* in_sizes, int n_in,
                              void* d_out, int out_size, void* d_ws, size_t ws_size,
                              hipStream_t stream)
{
  const float* query = (const float*)d_in[0];
  const float* key   = (const float*)d_in[1];
  const float* value = (const float*)d_in[2];
  const float* wq    = (const float*)d_in[3];
  const float* bq    = (const float*)d_in[4];
  const float* wk    = (const float*)d_in[5];
  const float* bk    = (const float*)d_in[6];
  const float* wv    = (const float*)d_in[7];
  const float* bv    = (const float*)d_in[8];
  const float* wo    = (const float*)d_in[9];
  const float* bo    = (const float*)d_in[10];

  const size_t seg = (size_t)M_ * D_;   // 4M elems (8MB bf16)
  u16* Qw  = (u16*)d_ws;                // [bh][s][d]
  u16* Kw  = Qw + seg;                  // [bh][s][d]
  u16* Vw  = Kw + seg;                  // [bh][d][s] (transposed)
  u16* Cw  = Vw + seg;                  // ctx [b][s][h*64]
  u16* wqb = Cw + seg;                  // bf16 weights, 256K elems each
  u16* wkb = wqb + (size_t)D_ * D_;
  u16* wvb = wkb + (size_t)D_ * D_;
  u16* wob = wvb + (size_t)D_ * D_;

  dim3 blk(256);
  convert_w<<<dim3((NG_W + 255) / 256), blk, 0, stream>>>(
      wq, wk, wv, wo, wqb, wkb, wvb, wob);
  gemm_qkv<<<dim3(M_ / 128, D_ / 128, 3), blk, 0, stream>>>(
      query, key, value, wqb, wkb, wvb, bq, bk, bv, Qw, Kw, Vw);
  attn_band_mfma<<<dim3((B_ * H_ * S_) / 64), blk, 0, stream>>>(Qw, Kw, Vw, Cw);
  gemm_out<<<dim3(M_ / 128, D_ / 128), blk, 0, stream>>>(Cw, wob, bo, (float*)d_out);
}

// Round 8
// 56.880 us; speedup vs baseline: 1.2050x; 1.2050x over previous
//
#include <hip/hip_runtime.h>
#include <hip/hip_bf16.h>

using u16 = unsigned short;
using u32 = unsigned int;

typedef float f32x4 __attribute__((ext_vector_type(4)));
typedef __bf16 bf16x8 __attribute__((ext_vector_type(8)));

constexpr int B_ = 2;
constexpr int S_ = 4096;
constexpr int D_ = 512;
constexpr int H_ = 8;
constexpr int DK_ = 64;
constexpr int M_ = B_ * S_;   // 8192
constexpr int K_ = 512;

__device__ __forceinline__ float bf2f(u16 u) {
  return __uint_as_float(((u32)u) << 16);
}
// fp32 -> bf16 round-to-nearest-even (inputs finite)
__device__ __forceinline__ u16 f2bf(float x) {
  u32 u = __float_as_uint(x);
  u = (u + 0x7fffu + ((u >> 16) & 1u)) >> 16;
  return (u16)u;
}
__device__ __forceinline__ u32 pack2(float a, float b) {
  return (u32)f2bf(a) | ((u32)f2bf(b) << 16);
}
// HW packed cvt: lo16 = bf16(a), hi16 = bf16(b)
__device__ __forceinline__ u32 cvtpk(float a, float b) {
  u32 r;
  asm("v_cvt_pk_bf16_f32 %0, %1, %2" : "=v"(r) : "v"(a), "v"(b));
  return r;
}

// async global->LDS, 16B per lane; LDS dest = wave-uniform base + lane*16
__device__ __forceinline__ void gload16(const void* g, void* l) {
  __builtin_amdgcn_global_load_lds((const __attribute__((address_space(1))) void*)g,
                                   (__attribute__((address_space(3))) void*)l,
                                   16, 0, 0);
}

// ---------------------------------------------------------------------------
// Prepass: convert the FOUR weight matrices to bf16 (1M elems, ~1.5us).
// Activations are converted inside gemm_qkv (LDS fp32 -> cvt_pk on frag load).
// ---------------------------------------------------------------------------
constexpr int NG_W = 4 * (262144 / 8);   // 131072 groups

__global__ __launch_bounds__(256) void convert_w(
    const float* __restrict__ wq, const float* __restrict__ wk,
    const float* __restrict__ wv, const float* __restrict__ wo,
    u16* __restrict__ wqb, u16* __restrict__ wkb, u16* __restrict__ wvb,
    u16* __restrict__ wob)
{
  const int g8 = blockIdx.x * 256 + threadIdx.x;
  if (g8 >= NG_W) return;
  const int t = g8 >> 15;          // 32768 groups per matrix
  const int r = g8 & 32767;
  const float* s = (t == 0) ? wq : (t == 1) ? wk : (t == 2) ? wv : wo;
  u16* d = (t == 0) ? wqb : (t == 1) ? wkb : (t == 2) ? wvb : wob;
  const size_t off = (size_t)r * 8;
  const float4 x = *(const float4*)(s + off);
  const float4 y = *(const float4*)(s + off + 4);
  uint4 o;
  o.x = pack2(x.x, x.y); o.y = pack2(x.z, x.w);
  o.z = pack2(y.x, y.y); o.w = pack2(y.z, y.w);
  *(uint4*)(d + off) = o;
}

// ---------------------------------------------------------------------------
// QKV GEMM, A fp32 staged RAW into LDS via global_load_lds (no VALU on the
// staging path); conversion happens on the LDS->reg fragment load via
// v_cvt_pk_bf16_f32 (throughput work, overlapped by 3 blocks/CU TLP).
//   C[m][n] = sum_k A[m][k]*W[n][k] + bias[n];  W bf16 (prepass), K=512.
// MODE 0: bf16 plain [M,512] (Q,K).  MODE 2: bf16 transposed [bh][d][s] (V).
// Tile 128x128, BK=64, 4 waves (2x2), wave tile 64x64.
// LDS: A fp32 128x64 (32KB, 256B rows, XOR (row&7)<<5) + B bf16 128x64
// (16KB, 128B rows, XOR (row&7)<<4); both linear-dest + pre-swizzled source.
// ---------------------------------------------------------------------------
template<int MODE>
__device__ __forceinline__ void gemm_qkv_body(const float* __restrict__ A,
                                              const u16* __restrict__ Wt,
                                              const float* __restrict__ bias,
                                              void* __restrict__ Cout,
                                              float* __restrict__ Asf,
                                              u16* __restrict__ Bs)
{
  const int tid  = threadIdx.x;
  const int lane = tid & 63;
  const int w    = tid >> 6;
  const int wm   = w >> 1;          // wave row: 64 m each
  const int wn   = w & 1;           // wave col: 64 n each
  const int m0   = blockIdx.x * 128;
  const int n0   = blockIdx.y * 128;
  const int qr   = lane & 15;
  const int g    = lane >> 4;

  // ---- A staging (fp32, 256B rows; 8 gload16/wave, 4 rows each) ----
  const int r4 = lane >> 4;                 // row-in-4 group
  const int c4 = (lane & 15) * 4;           // 16B chunk -> elem*4
  const int colx0 = c4 ^ (r4 << 3);         // p even
  const int colx1 = colx0 ^ 32;             // p odd (row bit2 set)
  const float* arow = A + (size_t)(m0 + w * 32 + r4) * K_;

  auto stage_A = [&](int t) {
    const float* base = arow + t * 64;
#pragma unroll
    for (int p = 0; p < 8; ++p)
      gload16(base + (size_t)(p * 4) * K_ + ((p & 1) ? colx1 : colx0),
              Asf + (w * 32 + p * 4) * 64);
  };

  // ---- B staging (bf16, 128B rows; 4 gload16/wave, 8 rows each) ----
  const int swz8 = ((lane & 7) ^ (lane >> 3)) * 8;
  const u16* b0 = Wt + (size_t)(n0 + w * 32 + (lane >> 3)) * K_ + swz8;
  auto stage_B = [&](int t) {
#pragma unroll
    for (int p = 0; p < 4; ++p)
      gload16(b0 + t * 64 + (size_t)p * 8 * K_, &Bs[(w * 32 + p * 8) * 64]);
  };

  f32x4 acc[4][4] = {};

  stage_A(0);
  stage_B(0);

  const int ax5 = (qr & 7) << 5;   // A read XOR (256B rows, 32B granule)
  const int ax4 = (qr & 7) << 4;   // B read XOR (128B rows, 16B granule)
  const char* ab = (const char*)Asf + (wm * 64 + qr) * 256;
  const char* bb = (const char*)Bs + (wn * 64 + qr) * 128;

  union U8 { u32 u[4]; bf16x8 v; };

  constexpr int NT = K_ / 64;  // 8
#pragma unroll 1
  for (int t = 0; t < NT; ++t) {
    __syncthreads();   // stage(t) drained (vmcnt) + visible to all waves

#pragma unroll
    for (int kk = 0; kk < 2; ++kk) {
      bf16x8 af[4], bfr[4];
#pragma unroll
      for (int i = 0; i < 4; ++i) {
        const char* p = ab + i * 4096 + ((g * 32 + kk * 128) ^ ax5);
        const f32x4 lo = *(const f32x4*)p;
        const f32x4 hi = *(const f32x4*)(p + 16);
        U8 u;
        u.u[0] = cvtpk(lo[0], lo[1]);
        u.u[1] = cvtpk(lo[2], lo[3]);
        u.u[2] = cvtpk(hi[0], hi[1]);
        u.u[3] = cvtpk(hi[2], hi[3]);
        af[i] = u.v;
      }
#pragma unroll
      for (int j = 0; j < 4; ++j)
        bfr[j] = *(const bf16x8*)(bb + j * 2048 + ((g * 16 + kk * 64) ^ ax4));
#pragma unroll
      for (int i = 0; i < 4; ++i)
#pragma unroll
        for (int j = 0; j < 4; ++j)
          acc[i][j] = __builtin_amdgcn_mfma_f32_16x16x32_bf16(af[i], bfr[j], acc[i][j], 0, 0, 0);
    }

    if (t + 1 < NT) {
      __syncthreads();           // all waves done reading buffers
      stage_A(t + 1);
      stage_B(t + 1);
    }
  }

  // epilogue: D frag layout col(n) = lane&15, row(m) = 4*(lane>>4)+r
#pragma unroll
  for (int j = 0; j < 4; ++j) {
    const int col = n0 + wn * 64 + j * 16 + qr;
    const float bv = bias[col];
#pragma unroll
    for (int i = 0; i < 4; ++i) {
      const int rbase = m0 + wm * 64 + i * 16 + g * 4;
      if constexpr (MODE == 2) {
        const int bb2 = rbase >> 12;
        const int ss = rbase & (S_ - 1);
        const int hh = col >> 6;
        const int dd = col & (DK_ - 1);
        uint2 pk;
        pk.x = pack2(acc[i][j][0] + bv, acc[i][j][1] + bv);
        pk.y = pack2(acc[i][j][2] + bv, acc[i][j][3] + bv);
        *(uint2*)&((u16*)Cout)[((size_t)((bb2 * H_ + hh) * DK_ + dd)) * S_ + ss] = pk;
      } else {
#pragma unroll
        for (int r = 0; r < 4; ++r)
          ((u16*)Cout)[(size_t)(rbase + r) * D_ + col] = f2bf(acc[i][j][r] + bv);
      }
    }
  }
}

__global__ __launch_bounds__(256, 3) void gemm_qkv(
    const float* __restrict__ q, const float* __restrict__ k, const float* __restrict__ v,
    const u16* __restrict__ wqb, const u16* __restrict__ wkb, const u16* __restrict__ wvb,
    const float* __restrict__ bq, const float* __restrict__ bk, const float* __restrict__ bv,
    u16* __restrict__ Qo, u16* __restrict__ Ko, u16* __restrict__ Vo)
{
  __shared__ float Asf[128 * 64];   // 32KB fp32
  __shared__ u16   Bs[128 * 64];    // 16KB bf16
  if (blockIdx.z == 0)      gemm_qkv_body<0>(q, wqb, bq, Qo, Asf, Bs);
  else if (blockIdx.z == 1) gemm_qkv_body<0>(k, wkb, bk, Ko, Asf, Bs);
  else                      gemm_qkv_body<2>(v, wvb, bv, Vo, Asf, Bs);  // V transposed
}

// ---------------------------------------------------------------------------
// Output GEMM: A bf16 (ctx, plain [M,512]), W bf16, fp32 out [M,512].
// Tile 64x128 -> 512 blocks = 2/CU (was 1/CU at 128x128).
// ---------------------------------------------------------------------------
__global__ __launch_bounds__(256, 2) void gemm_out(
    const u16* __restrict__ A, const u16* __restrict__ Wt,
    const float* __restrict__ bias, float* __restrict__ C)
{
  __shared__ u16 As[64 * 64];    // 8KB
  __shared__ u16 Bs[128 * 64];   // 16KB

  const int tid  = threadIdx.x;
  const int lane = tid & 63;
  const int w    = tid >> 6;
  const int wm   = w >> 1;       // 32 m-rows each
  const int wn   = w & 1;        // 64 n-cols each
  const int m0   = blockIdx.x * 64;
  const int n0   = blockIdx.y * 128;
  const int qr   = lane & 15;
  const int g    = lane >> 4;

  const int swz8 = ((lane & 7) ^ (lane >> 3)) * 8;
  const u16* a0 = A  + (size_t)(m0 + w * 16 + (lane >> 3)) * K_ + swz8;
  const u16* b0 = Wt + (size_t)(n0 + w * 32 + (lane >> 3)) * K_ + swz8;

  auto stage = [&](int t) {
#pragma unroll
    for (int p = 0; p < 2; ++p)
      gload16(a0 + t * 64 + (size_t)p * 8 * K_, &As[(w * 16 + p * 8) * 64]);
#pragma unroll
    for (int p = 0; p < 4; ++p)
      gload16(b0 + t * 64 + (size_t)p * 8 * K_, &Bs[(w * 32 + p * 8) * 64]);
  };

  f32x4 acc[2][4] = {};
  stage(0);

  const int ax = (qr & 7) << 4;
  const char* ab = (const char*)As + (wm * 32 + qr) * 128;
  const char* bb = (const char*)Bs + (wn * 64 + qr) * 128;

  constexpr int NT = K_ / 64;
#pragma unroll 1
  for (int t = 0; t < NT; ++t) {
    __syncthreads();
#pragma unroll
    for (int kk = 0; kk < 2; ++kk) {
      bf16x8 af[2], bfr[4];
#pragma unroll
      for (int i = 0; i < 2; ++i)
        af[i]  = *(const bf16x8*)(ab + i * 2048 + ((g * 16 + kk * 64) ^ ax));
#pragma unroll
      for (int j = 0; j < 4; ++j)
        bfr[j] = *(const bf16x8*)(bb + j * 2048 + ((g * 16 + kk * 64) ^ ax));
#pragma unroll
      for (int i = 0; i < 2; ++i)
#pragma unroll
        for (int j = 0; j < 4; ++j)
          acc[i][j] = __builtin_amdgcn_mfma_f32_16x16x32_bf16(af[i], bfr[j], acc[i][j], 0, 0, 0);
    }
    if (t + 1 < NT) {
      __syncthreads();
      stage(t + 1);
    }
  }

#pragma unroll
  for (int j = 0; j < 4; ++j) {
    const int col = n0 + wn * 64 + j * 16 + qr;
    const float bv = bias[col];
#pragma unroll
    for (int i = 0; i < 2; ++i) {
      const int rbase = m0 + wm * 32 + i * 16 + g * 4;
#pragma unroll
      for (int r = 0; r < 4; ++r)
        C[(size_t)(rbase + r) * D_ + col] = acc[i][j][r] + bv;
    }
  }
}

// ---------------------------------------------------------------------------
// MFMA banded attention. One wave per 16-query tile. Q,K read from PLAIN
// [M,512] layout (head slice = contiguous 64 cols); V from [bh][d][s].
// ---------------------------------------------------------------------------
__global__ __launch_bounds__(256) void attn_band_mfma(
    const u16* __restrict__ Q, const u16* __restrict__ K,
    const u16* __restrict__ Vt, u16* __restrict__ Ctx)
{
  constexpr int LDP = 72;
  __shared__ u16 P_lds[4][16 * LDP];

  const int lane = threadIdx.x & 63;
  const int w    = threadIdx.x >> 6;
  const int wid  = blockIdx.x * 4 + w;
  const int q0   = (wid & 255) << 4;
  const int bh   = wid >> 8;
  const int bb   = bh >> 3;
  const int hh   = bh & (H_ - 1);

  u16* pl = &P_lds[w][0];
  const int qr = lane & 15;
  const int g  = lane >> 4;

  *(uint2*)&pl[qr * LDP + 48 + 4 * g] = make_uint2(0u, 0u);

  bf16x8 qf[2];
  {
    const u16* qp = Q + ((size_t)(bb * S_ + q0 + qr)) * D_ + hh * DK_ + 8 * g;
    qf[0] = *(const bf16x8*)qp;
    qf[1] = *(const bf16x8*)(qp + 32);
  }

  f32x4 sc[3];
#pragma unroll
  for (int t = 0; t < 3; ++t) {
    int j = q0 - 16 + 16 * t + qr;
    j = min(max(j, 0), S_ - 1);
    const u16* kp = K + ((size_t)(bb * S_ + j)) * D_ + hh * DK_ + 8 * g;
    const bf16x8 kf0 = *(const bf16x8*)kp;
    const bf16x8 kf1 = *(const bf16x8*)(kp + 32);
    f32x4 a = {};
    a = __builtin_amdgcn_mfma_f32_16x16x32_bf16(kf0, qf[0], a, 0, 0, 0);
    a = __builtin_amdgcn_mfma_f32_16x16x32_bf16(kf1, qf[1], a, 0, 0, 0);
    sc[t] = a;
  }

  float s[3][4];
  float mx = -INFINITY;
#pragma unroll
  for (int t = 0; t < 3; ++t)
#pragma unroll
    for (int r = 0; r < 4; ++r) {
      const int joff = 16 * t + 4 * g + r;
      const int j = q0 - 16 + joff;
      const bool ok = (joff >= qr) && (joff <= qr + 32) && (j >= 0) && (j < S_);
      const float v = ok ? sc[t][r] * 0.125f : -INFINITY;
      s[t][r] = v;
      mx = fmaxf(mx, v);
    }
  mx = fmaxf(mx, __shfl_xor(mx, 16));
  mx = fmaxf(mx, __shfl_xor(mx, 32));

  float p[3][4];
  float den = 0.f;
#pragma unroll
  for (int t = 0; t < 3; ++t)
#pragma unroll
    for (int r = 0; r < 4; ++r) {
      p[t][r] = __expf(s[t][r] - mx);
      den += p[t][r];
    }
  den += __shfl_xor(den, 16);
  den += __shfl_xor(den, 32);
  const float inv = 1.0f / den;

#pragma unroll
  for (int t = 0; t < 3; ++t) {
    uint2 pk;
    pk.x = pack2(p[t][0] * inv, p[t][1] * inv);
    pk.y = pack2(p[t][2] * inv, p[t][3] * inv);
    *(uint2*)&pl[qr * LDP + 16 * t + 4 * g] = pk;
  }

  f32x4 cacc[4] = {};
#pragma unroll
  for (int jc = 0; jc < 2; ++jc) {
    const bf16x8 pa = *(const bf16x8*)&pl[qr * LDP + 8 * g + 32 * jc];
#pragma unroll
    for (int nt = 0; nt < 4; ++nt) {
      int jj = q0 - 16 + 8 * g + 32 * jc;
      jj = min(max(jj, 0), S_ - 8);
      const u16* vp = Vt + ((size_t)bh * DK_ + 16 * nt + qr) * S_ + jj;
      const bf16x8 vf = *(const bf16x8*)vp;
      cacc[nt] = __builtin_amdgcn_mfma_f32_16x16x32_bf16(pa, vf, cacc[nt], 0, 0, 0);
    }
  }

#pragma unroll
  for (int nt = 0; nt < 4; ++nt)
#pragma unroll
    for (int r = 0; r < 4; ++r) {
      const int qq = 4 * g + r;
      const int dd = 16 * nt + qr;
      Ctx[((size_t)(bb * S_ + q0 + qq)) * D_ + hh * DK_ + dd] = f2bf(cacc[nt][r]);
    }
}

// ---------------------------------------------------------------------------
extern "C" void kernel_launch(void* const* d_in, const int* in_sizes, int n_in,
                              void* d_out, int out_size, void* d_ws, size_t ws_size,
                              hipStream_t stream)
{
  const float* query = (const float*)d_in[0];
  const float* key   = (const float*)d_in[1];
  const float* value = (const float*)d_in[2];
  const float* wq    = (const float*)d_in[3];
  const float* bq    = (const float*)d_in[4];
  const float* wk    = (const float*)d_in[5];
  const float* bk    = (const float*)d_in[6];
  const float* wv    = (const float*)d_in[7];
  const float* bv    = (const float*)d_in[8];
  const float* wo    = (const float*)d_in[9];
  const float* bo    = (const float*)d_in[10];

  const size_t seg = (size_t)M_ * D_;   // 4M elems (8MB bf16)
  u16* Qw  = (u16*)d_ws;                // plain [M][512] bf16
  u16* Kw  = Qw + seg;                  // plain [M][512] bf16
  u16* Vw  = Kw + seg;                  // [bh][d][s] bf16 (transposed)
  u16* Cw  = Vw + seg;                  // ctx plain [M][512] bf16
  u16* wqb = Cw + seg;                  // bf16 weights, 256K elems each
  u16* wkb = wqb + (size_t)D_ * D_;
  u16* wvb = wkb + (size_t)D_ * D_;
  u16* wob = wvb + (size_t)D_ * D_;

  dim3 blk(256);
  convert_w<<<dim3((NG_W + 255) / 256), blk, 0, stream>>>(
      wq, wk, wv, wo, wqb, wkb, wvb, wob);
  gemm_qkv<<<dim3(M_ / 128, D_ / 128, 3), blk, 0, stream>>>(
      query, key, value, wqb, wkb, wvb, bq, bk, bv, Qw, Kw, Vw);
  attn_band_mfma<<<dim3((B_ * H_ * S_) / 64), blk, 0, stream>>>(Qw, Kw, Vw, Cw);
  gemm_out<<<dim3(M_ / 64, D_ / 128), blk, 0, stream>>>(Cw, wob, bo, (float*)d_out);
}

// Round 9
// 55.032 us; speedup vs baseline: 1.2455x; 1.0336x over previous
//
#include <hip/hip_runtime.h>
#include <hip/hip_bf16.h>

using u16 = unsigned short;
using u32 = unsigned int;

typedef float f32x4 __attribute__((ext_vector_type(4)));
typedef __bf16 bf16x8 __attribute__((ext_vector_type(8)));

constexpr int B_ = 2;
constexpr int S_ = 4096;
constexpr int D_ = 512;
constexpr int H_ = 8;
constexpr int DK_ = 64;
constexpr int M_ = B_ * S_;   // 8192
constexpr int K_ = 512;

__device__ __forceinline__ float bf2f(u16 u) {
  return __uint_as_float(((u32)u) << 16);
}
// fp32 -> bf16 round-to-nearest-even (inputs finite)
__device__ __forceinline__ u16 f2bf(float x) {
  u32 u = __float_as_uint(x);
  u = (u + 0x7fffu + ((u >> 16) & 1u)) >> 16;
  return (u16)u;
}
__device__ __forceinline__ u32 pack2(float a, float b) {
  return (u32)f2bf(a) | ((u32)f2bf(b) << 16);
}
// HW packed cvt: lo16 = bf16(a), hi16 = bf16(b)
__device__ __forceinline__ u32 cvtpk(float a, float b) {
  u32 r;
  asm("v_cvt_pk_bf16_f32 %0, %1, %2" : "=v"(r) : "v"(a), "v"(b));
  return r;
}

// async global->LDS, 16B per lane; LDS dest = wave-uniform base + lane*16
__device__ __forceinline__ void gload16(const void* g, void* l) {
  __builtin_amdgcn_global_load_lds((const __attribute__((address_space(1))) void*)g,
                                   (__attribute__((address_space(3))) void*)l,
                                   16, 0, 0);
}

// ---------------------------------------------------------------------------
// Prepass: convert the FOUR weight matrices to bf16 (1M elems, ~1.5us).
// ---------------------------------------------------------------------------
constexpr int NG_W = 4 * (262144 / 8);   // 131072 groups

__global__ __launch_bounds__(256) void convert_w(
    const float* __restrict__ wq, const float* __restrict__ wk,
    const float* __restrict__ wv, const float* __restrict__ wo,
    u16* __restrict__ wqb, u16* __restrict__ wkb, u16* __restrict__ wvb,
    u16* __restrict__ wob)
{
  const int g8 = blockIdx.x * 256 + threadIdx.x;
  if (g8 >= NG_W) return;
  const int t = g8 >> 15;          // 32768 groups per matrix
  const int r = g8 & 32767;
  const float* s = (t == 0) ? wq : (t == 1) ? wk : (t == 2) ? wv : wo;
  u16* d = (t == 0) ? wqb : (t == 1) ? wkb : (t == 2) ? wvb : wob;
  const size_t off = (size_t)r * 8;
  const float4 x = *(const float4*)(s + off);
  const float4 y = *(const float4*)(s + off + 4);
  uint4 o;
  o.x = pack2(x.x, x.y); o.y = pack2(x.z, x.w);
  o.z = pack2(y.x, y.y); o.w = pack2(y.z, y.w);
  *(uint4*)(d + off) = o;
}

// ---------------------------------------------------------------------------
// QKV GEMM, A fp32 reg-staged -> cvt_pk -> bf16 LDS (T14 full split: ALL
// next-tile loads issued before the compute phase; cvt+ds_write after the
// 2nd barrier).  C[m][n] = sum_k A[m][k]*W[n][k] + bias[n]; W bf16 prepass.
// MODE 0: bf16 plain [M,512] (Q,K).  MODE 2: bf16 transposed [bh][d][s] (V).
// Tile 128x128, BK=64, 4 waves (2x2), wave tile 64x64.
// LDS: A bf16 128x64 (16KB) + B bf16 128x64 (16KB), 128B rows, XOR swizzle
// granule^(row&7); A swizzled on ds_write addr, B via pre-swizzled global
// source + linear DMA dest (T21 both-sides on each path).
// ---------------------------------------------------------------------------
template<int MODE>
__device__ __forceinline__ void gemm_qkv_body(const float* __restrict__ A,
                                              const u16* __restrict__ Wt,
                                              const float* __restrict__ bias,
                                              void* __restrict__ Cout,
                                              u16* __restrict__ As,
                                              u16* __restrict__ Bs)
{
  const int tid  = threadIdx.x;
  const int lane = tid & 63;
  const int w    = tid >> 6;
  const int wm   = w >> 1;          // wave row: 64 m each
  const int wn   = w & 1;           // wave col: 64 n each
  const int m0   = blockIdx.x * 128;
  const int n0   = blockIdx.y * 128;
  const int qr   = lane & 15;
  const int g    = lane >> 4;

  // ---- A staging: thread owns rows sr8+32p, col chunk c8 (8 elems) ----
  const int sr8 = tid >> 3;         // 0..31
  const int c8  = tid & 7;
  const float* afp = A + (size_t)(m0 + sr8) * K_ + c8 * 8;
  char* awr = (char*)As + sr8 * 128 + ((c8 ^ (sr8 & 7)) * 16);  // swizzled

  float4 ax_[4], ay_[4];
  auto a_issue = [&](int t) {       // 8x global_load_dwordx4, issued EARLY
#pragma unroll
    for (int p = 0; p < 4; ++p) {
      const float* s = afp + t * 64 + (size_t)(p * 32) * K_;
      ax_[p] = *(const float4*)s;
      ay_[p] = *(const float4*)(s + 4);
    }
  };
  auto a_write = [&]() {            // cvt_pk + 4x ds_write_b128, LATE
#pragma unroll
    for (int p = 0; p < 4; ++p) {
      uint4 o;
      o.x = cvtpk(ax_[p].x, ax_[p].y);
      o.y = cvtpk(ax_[p].z, ax_[p].w);
      o.z = cvtpk(ay_[p].x, ay_[p].y);
      o.w = cvtpk(ay_[p].z, ay_[p].w);
      *(uint4*)(awr + p * 32 * 128) = o;
    }
  };

  // ---- B staging (bf16 DMA; linear dest + pre-swizzled source) ----
  const int swz8 = ((lane & 7) ^ (lane >> 3)) * 8;
  const u16* b0 = Wt + (size_t)(n0 + w * 32 + (lane >> 3)) * K_ + swz8;
  auto stage_B = [&](int t) {
#pragma unroll
    for (int p = 0; p < 4; ++p)
      gload16(b0 + t * 64 + (size_t)p * 8 * K_, &Bs[(w * 32 + p * 8) * 64]);
  };

  f32x4 acc[4][4] = {};

  // prologue: tile 0
  a_issue(0);
  a_write();
  stage_B(0);

  const int axr = (qr & 7) << 4;
  const char* ab = (const char*)As + (wm * 64 + qr) * 128;
  const char* bb = (const char*)Bs + (wn * 64 + qr) * 128;

  constexpr int NT = K_ / 64;  // 8
#pragma unroll 1
  for (int t = 0; t < NT; ++t) {
    __syncthreads();   // tile t resident (ds_write lgkm + DMA vmcnt drained)

    if (t + 1 < NT) a_issue(t + 1);   // loads in flight across compute

#pragma unroll
    for (int kk = 0; kk < 2; ++kk) {
      bf16x8 af[4], bfr[4];
#pragma unroll
      for (int i = 0; i < 4; ++i)
        af[i]  = *(const bf16x8*)(ab + i * 2048 + ((g * 16 + kk * 64) ^ axr));
#pragma unroll
      for (int j = 0; j < 4; ++j)
        bfr[j] = *(const bf16x8*)(bb + j * 2048 + ((g * 16 + kk * 64) ^ axr));
#pragma unroll
      for (int i = 0; i < 4; ++i)
#pragma unroll
        for (int j = 0; j < 4; ++j)
          acc[i][j] = __builtin_amdgcn_mfma_f32_16x16x32_bf16(af[i], bfr[j], acc[i][j], 0, 0, 0);
    }

    if (t + 1 < NT) {
      __syncthreads();   // all waves done reading tile t
      a_write();         // waits the (long-issued) loads, cvt, swizzled write
      stage_B(t + 1);
    }
  }

  // epilogue: D frag layout col(n) = lane&15, row(m) = 4*(lane>>4)+r
#pragma unroll
  for (int j = 0; j < 4; ++j) {
    const int col = n0 + wn * 64 + j * 16 + qr;
    const float bv = bias[col];
#pragma unroll
    for (int i = 0; i < 4; ++i) {
      const int rbase = m0 + wm * 64 + i * 16 + g * 4;
      if constexpr (MODE == 2) {
        const int bb2 = rbase >> 12;
        const int ss = rbase & (S_ - 1);
        const int hh = col >> 6;
        const int dd = col & (DK_ - 1);
        uint2 pk;
        pk.x = pack2(acc[i][j][0] + bv, acc[i][j][1] + bv);
        pk.y = pack2(acc[i][j][2] + bv, acc[i][j][3] + bv);
        *(uint2*)&((u16*)Cout)[((size_t)((bb2 * H_ + hh) * DK_ + dd)) * S_ + ss] = pk;
      } else {
#pragma unroll
        for (int r = 0; r < 4; ++r)
          ((u16*)Cout)[(size_t)(rbase + r) * D_ + col] = f2bf(acc[i][j][r] + bv);
      }
    }
  }
}

__global__ __launch_bounds__(256, 3) void gemm_qkv(
    const float* __restrict__ q, const float* __restrict__ k, const float* __restrict__ v,
    const u16* __restrict__ wqb, const u16* __restrict__ wkb, const u16* __restrict__ wvb,
    const float* __restrict__ bq, const float* __restrict__ bk, const float* __restrict__ bv,
    u16* __restrict__ Qo, u16* __restrict__ Ko, u16* __restrict__ Vo)
{
  __shared__ u16 As[128 * 64];   // 16KB bf16
  __shared__ u16 Bs[128 * 64];   // 16KB bf16
  if (blockIdx.z == 0)      gemm_qkv_body<0>(q, wqb, bq, Qo, As, Bs);
  else if (blockIdx.z == 1) gemm_qkv_body<0>(k, wkb, bk, Ko, As, Bs);
  else                      gemm_qkv_body<2>(v, wvb, bv, Vo, As, Bs);  // V transposed
}

// ---------------------------------------------------------------------------
// Output GEMM: A bf16 (ctx, plain [M,512]), W bf16, fp32 out [M,512].
// Tile 64x128 -> 512 blocks = 2/CU. (unchanged from round 8)
// ---------------------------------------------------------------------------
__global__ __launch_bounds__(256, 2) void gemm_out(
    const u16* __restrict__ A, const u16* __restrict__ Wt,
    const float* __restrict__ bias, float* __restrict__ C)
{
  __shared__ u16 As[64 * 64];    // 8KB
  __shared__ u16 Bs[128 * 64];   // 16KB

  const int tid  = threadIdx.x;
  const int lane = tid & 63;
  const int w    = tid >> 6;
  const int wm   = w >> 1;       // 32 m-rows each
  const int wn   = w & 1;        // 64 n-cols each
  const int m0   = blockIdx.x * 64;
  const int n0   = blockIdx.y * 128;
  const int qr   = lane & 15;
  const int g    = lane >> 4;

  const int swz8 = ((lane & 7) ^ (lane >> 3)) * 8;
  const u16* a0 = A  + (size_t)(m0 + w * 16 + (lane >> 3)) * K_ + swz8;
  const u16* b0 = Wt + (size_t)(n0 + w * 32 + (lane >> 3)) * K_ + swz8;

  auto stage = [&](int t) {
#pragma unroll
    for (int p = 0; p < 2; ++p)
      gload16(a0 + t * 64 + (size_t)p * 8 * K_, &As[(w * 16 + p * 8) * 64]);
#pragma unroll
    for (int p = 0; p < 4; ++p)
      gload16(b0 + t * 64 + (size_t)p * 8 * K_, &Bs[(w * 32 + p * 8) * 64]);
  };

  f32x4 acc[2][4] = {};
  stage(0);

  const int ax = (qr & 7) << 4;
  const char* ab = (const char*)As + (wm * 32 + qr) * 128;
  const char* bb = (const char*)Bs + (wn * 64 + qr) * 128;

  constexpr int NT = K_ / 64;
#pragma unroll 1
  for (int t = 0; t < NT; ++t) {
    __syncthreads();
#pragma unroll
    for (int kk = 0; kk < 2; ++kk) {
      bf16x8 af[2], bfr[4];
#pragma unroll
      for (int i = 0; i < 2; ++i)
        af[i]  = *(const bf16x8*)(ab + i * 2048 + ((g * 16 + kk * 64) ^ ax));
#pragma unroll
      for (int j = 0; j < 4; ++j)
        bfr[j] = *(const bf16x8*)(bb + j * 2048 + ((g * 16 + kk * 64) ^ ax));
#pragma unroll
      for (int i = 0; i < 2; ++i)
#pragma unroll
        for (int j = 0; j < 4; ++j)
          acc[i][j] = __builtin_amdgcn_mfma_f32_16x16x32_bf16(af[i], bfr[j], acc[i][j], 0, 0, 0);
    }
    if (t + 1 < NT) {
      __syncthreads();
      stage(t + 1);
    }
  }

#pragma unroll
  for (int j = 0; j < 4; ++j) {
    const int col = n0 + wn * 64 + j * 16 + qr;
    const float bv = bias[col];
#pragma unroll
    for (int i = 0; i < 2; ++i) {
      const int rbase = m0 + wm * 32 + i * 16 + g * 4;
#pragma unroll
      for (int r = 0; r < 4; ++r)
        C[(size_t)(rbase + r) * D_ + col] = acc[i][j][r] + bv;
    }
  }
}

// ---------------------------------------------------------------------------
// MFMA banded attention. One wave per 16-query tile. Q,K read from PLAIN
// [M,512] layout (head slice = contiguous 64 cols); V from [bh][d][s].
// (unchanged from round 8)
// ---------------------------------------------------------------------------
__global__ __launch_bounds__(256) void attn_band_mfma(
    const u16* __restrict__ Q, const u16* __restrict__ K,
    const u16* __restrict__ Vt, u16* __restrict__ Ctx)
{
  constexpr int LDP = 72;
  __shared__ u16 P_lds[4][16 * LDP];

  const int lane = threadIdx.x & 63;
  const int w    = threadIdx.x >> 6;
  const int wid  = blockIdx.x * 4 + w;
  const int q0   = (wid & 255) << 4;
  const int bh   = wid >> 8;
  const int bb   = bh >> 3;
  const int hh   = bh & (H_ - 1);

  u16* pl = &P_lds[w][0];
  const int qr = lane & 15;
  const int g  = lane >> 4;

  *(uint2*)&pl[qr * LDP + 48 + 4 * g] = make_uint2(0u, 0u);

  bf16x8 qf[2];
  {
    const u16* qp = Q + ((size_t)(bb * S_ + q0 + qr)) * D_ + hh * DK_ + 8 * g;
    qf[0] = *(const bf16x8*)qp;
    qf[1] = *(const bf16x8*)(qp + 32);
  }

  f32x4 sc[3];
#pragma unroll
  for (int t = 0; t < 3; ++t) {
    int j = q0 - 16 + 16 * t + qr;
    j = min(max(j, 0), S_ - 1);
    const u16* kp = K + ((size_t)(bb * S_ + j)) * D_ + hh * DK_ + 8 * g;
    const bf16x8 kf0 = *(const bf16x8*)kp;
    const bf16x8 kf1 = *(const bf16x8*)(kp + 32);
    f32x4 a = {};
    a = __builtin_amdgcn_mfma_f32_16x16x32_bf16(kf0, qf[0], a, 0, 0, 0);
    a = __builtin_amdgcn_mfma_f32_16x16x32_bf16(kf1, qf[1], a, 0, 0, 0);
    sc[t] = a;
  }

  float s[3][4];
  float mx = -INFINITY;
#pragma unroll
  for (int t = 0; t < 3; ++t)
#pragma unroll
    for (int r = 0; r < 4; ++r) {
      const int joff = 16 * t + 4 * g + r;
      const int j = q0 - 16 + joff;
      const bool ok = (joff >= qr) && (joff <= qr + 32) && (j >= 0) && (j < S_);
      const float v = ok ? sc[t][r] * 0.125f : -INFINITY;
      s[t][r] = v;
      mx = fmaxf(mx, v);
    }
  mx = fmaxf(mx, __shfl_xor(mx, 16));
  mx = fmaxf(mx, __shfl_xor(mx, 32));

  float p[3][4];
  float den = 0.f;
#pragma unroll
  for (int t = 0; t < 3; ++t)
#pragma unroll
    for (int r = 0; r < 4; ++r) {
      p[t][r] = __expf(s[t][r] - mx);
      den += p[t][r];
    }
  den += __shfl_xor(den, 16);
  den += __shfl_xor(den, 32);
  const float inv = 1.0f / den;

#pragma unroll
  for (int t = 0; t < 3; ++t) {
    uint2 pk;
    pk.x = pack2(p[t][0] * inv, p[t][1] * inv);
    pk.y = pack2(p[t][2] * inv, p[t][3] * inv);
    *(uint2*)&pl[qr * LDP + 16 * t + 4 * g] = pk;
  }

  f32x4 cacc[4] = {};
#pragma unroll
  for (int jc = 0; jc < 2; ++jc) {
    const bf16x8 pa = *(const bf16x8*)&pl[qr * LDP + 8 * g + 32 * jc];
#pragma unroll
    for (int nt = 0; nt < 4; ++nt) {
      int jj = q0 - 16 + 8 * g + 32 * jc;
      jj = min(max(jj, 0), S_ - 8);
      const u16* vp = Vt + ((size_t)bh * DK_ + 16 * nt + qr) * S_ + jj;
      const bf16x8 vf = *(const bf16x8*)vp;
      cacc[nt] = __builtin_amdgcn_mfma_f32_16x16x32_bf16(pa, vf, cacc[nt], 0, 0, 0);
    }
  }

#pragma unroll
  for (int nt = 0; nt < 4; ++nt)
#pragma unroll
    for (int r = 0; r < 4; ++r) {
      const int qq = 4 * g + r;
      const int dd = 16 * nt + qr;
      Ctx[((size_t)(bb * S_ + q0 + qq)) * D_ + hh * DK_ + dd] = f2bf(cacc[nt][r]);
    }
}

// ---------------------------------------------------------------------------
extern "C" void kernel_launch(void* const* d_in, const int* in_sizes, int n_in,
                              void* d_out, int out_size, void* d_ws, size_t ws_size,
                              hipStream_t stream)
{
  const float* query = (const float*)d_in[0];
  const float* key   = (const float*)d_in[1];
  const float* value = (const float*)d_in[2];
  const float* wq    = (const float*)d_in[3];
  const float* bq    = (const float*)d_in[4];
  const float* wk    = (const float*)d_in[5];
  const float* bk    = (const float*)d_in[6];
  const float* wv    = (const float*)d_in[7];
  const float* bv    = (const float*)d_in[8];
  const float* wo    = (const float*)d_in[9];
  const float* bo    = (const float*)d_in[10];

  const size_t seg = (size_t)M_ * D_;   // 4M elems (8MB bf16)
  u16* Qw  = (u16*)d_ws;                // plain [M][512] bf16
  u16* Kw  = Qw + seg;                  // plain [M][512] bf16
  u16* Vw  = Kw + seg;                  // [bh][d][s] bf16 (transposed)
  u16* Cw  = Vw + seg;                  // ctx plain [M][512] bf16
  u16* wqb = Cw + seg;                  // bf16 weights, 256K elems each
  u16* wkb = wqb + (size_t)D_ * D_;
  u16* wvb = wkb + (size_t)D_ * D_;
  u16* wob = wvb + (size_t)D_ * D_;

  dim3 blk(256);
  convert_w<<<dim3((NG_W + 255) / 256), blk, 0, stream>>>(
      wq, wk, wv, wo, wqb, wkb, wvb, wob);
  gemm_qkv<<<dim3(M_ / 128, D_ / 128, 3), blk, 0, stream>>>(
      query, key, value, wqb, wkb, wvb, bq, bk, bv, Qw, Kw, Vw);
  attn_band_mfma<<<dim3((B_ * H_ * S_) / 64), blk, 0, stream>>>(Qw, Kw, Vw, Cw);
  gemm_out<<<dim3(M_ / 64, D_ / 128), blk, 0, stream>>>(Cw, wob, bo, (float*)d_out);
}